// Round 1
// baseline (305.366 us; speedup 1.0000x reference)
//
#include <hip/hip_runtime.h>

#define Bb 32
#define Nn 512
#define Dd 256
#define KC 1792   // 256 (self) + 6*256 (edge types)

typedef __bf16 bf16x8 __attribute__((ext_vector_type(8)));
typedef float  f32x4  __attribute__((ext_vector_type(4)));
typedef unsigned short u16;

__device__ __forceinline__ u16 f2bf(float x){
  union { float f; unsigned u; } c; c.f = x;
  unsigned u = c.u;
  u += 0x7FFFu + ((u >> 16) & 1u);   // RNE
  return (u16)(u >> 16);
}

// ---------------- K0: WcatT[e][c] = Wcat[c][e] in bf16, [256 x 1792] -------
__global__ __launch_bounds__(256) void k_prep(
    const float* __restrict__ wself,
    const float* __restrict__ w0, const float* __restrict__ w1,
    const float* __restrict__ w2, const float* __restrict__ w3,
    const float* __restrict__ w4, const float* __restrict__ w5,
    u16* __restrict__ wcatT){
  int e = blockIdx.x;
  const float* Ws[7] = {wself, w0, w1, w2, w3, w4, w5};
  for (int c = threadIdx.x; c < KC; c += 256){
    int g = c >> 8, j = c & 255;
    wcatT[(size_t)e*KC + c] = f2bf(Ws[g][j*Dd + e]);
  }
}

// ---------------- K1: rs[b,m] = mask[m] / max(nn,1), nn = sum_k,n G --------
__global__ __launch_bounds__(256) void k_nn(
    const int* __restrict__ g0, const int* __restrict__ g1,
    const int* __restrict__ g2, const int* __restrict__ g3,
    const int* __restrict__ g4, const int* __restrict__ g5,
    const int* __restrict__ mask, float* __restrict__ rs){
  int wid = threadIdx.x >> 6, lane = threadIdx.x & 63;
  int r = blockIdx.x * 4 + wid;          // r = b*512 + m
  int b = r >> 9, m = r & 511;
  const int* gs[6] = {g0, g1, g2, g3, g4, g5};
  const int4* mk = (const int4*)(mask + (size_t)b * Nn);
  int s = 0;
  #pragma unroll
  for (int k = 0; k < 6; ++k){
    const int4* gp = (const int4*)(gs[k] + (size_t)r * Nn);
    #pragma unroll
    for (int h = 0; h < 2; ++h){
      int idx = lane + h * 64;
      int4 gv = gp[idx];
      int4 mv = mk[idx];
      int c0 = idx * 4;
      s += (gv.x && mv.x && (c0 + 0) != m);
      s += (gv.y && mv.y && (c0 + 1) != m);
      s += (gv.z && mv.z && (c0 + 2) != m);
      s += (gv.w && mv.w && (c0 + 3) != m);
    }
  }
  #pragma unroll
  for (int off = 32; off; off >>= 1) s += __shfl_down(s, off);
  if (lane == 0){
    int mm = mask[r];
    rs[r] = mm ? 1.0f / (float)(s < 1 ? 1 : s) : 0.0f;
  }
}

// ---------------- K2: dw (sigmoid), Z node copy (bf16), X'^T build ---------
// block: 256 thr, tile = 32 rows (n) x 256 cols (d) of node
__global__ __launch_bounds__(256) void k_dw(
    const float* __restrict__ node, const int* __restrict__ mask,
    const float* __restrict__ wnw, const float* __restrict__ bnw,
    float* __restrict__ aw_out,    // already offset by t*N
    u16* __restrict__ Z, u16* __restrict__ XT){
  __shared__ float tile[32][268];
  __shared__ float dws[32];
  int b = blockIdx.x >> 4, n0 = (blockIdx.x & 15) << 5;
  int t = threadIdx.x;
  int row = t >> 3, seg = t & 7;
  const float* src = node + ((size_t)(b * Nn + n0 + row)) * Dd + seg * 32;
  u16* zn = Z + ((size_t)(b * Nn + n0 + row)) * KC + seg * 32;
  #pragma unroll
  for (int c = 0; c < 8; ++c){
    float4 v = ((const float4*)src)[c];
    tile[row][seg * 32 + c * 4 + 0] = v.x;
    tile[row][seg * 32 + c * 4 + 1] = v.y;
    tile[row][seg * 32 + c * 4 + 2] = v.z;
    tile[row][seg * 32 + c * 4 + 3] = v.w;
    ushort4 h;
    h.x = f2bf(v.x); h.y = f2bf(v.y); h.z = f2bf(v.z); h.w = f2bf(v.w);
    ((ushort4*)zn)[c] = h;
  }
  __syncthreads();
  float s = 0.f;
  #pragma unroll
  for (int c = 0; c < 32; ++c) s += tile[row][seg * 32 + c] * wnw[seg * 32 + c];
  s += __shfl_xor(s, 1); s += __shfl_xor(s, 2); s += __shfl_xor(s, 4);
  if (seg == 0){
    float dw = 1.f / (1.f + expf(-(s + bnw[0])));
    aw_out[b * (2 * Nn) + n0 + row] = dw;                 // raw dw to output
    dws[row] = mask[b * Nn + n0 + row] ? dw : 0.f;        // mask[n] folded
  }
  __syncthreads();
  // X'^T[d][n] = bf16(dw[n]*node[n][d]); XT layout [B][256][512]
  #pragma unroll
  for (int p = 0; p < 4; ++p){
    int d = p * 64 + (t >> 2);
    int j0 = (t & 3) * 8;
    union { u16 h[8]; uint4 v; } pk;
    #pragma unroll
    for (int jj = 0; jj < 8; ++jj)
      pk.h[jj] = f2bf(dws[j0 + jj] * tile[j0 + jj][d]);
    *(uint4*)(XT + ((size_t)(b * Dd + d)) * Nn + n0 + j0) = pk.v;
  }
}

// ---------------- K3: aggregation GEMM  H'_k = rs * (G_k @ X') ------------
// grid (8, 32, 6): mtile, b, edge-type.  BM=64, BN=256(full D), BK=64, 4 waves
__global__ __launch_bounds__(256) void k_agg(
    const int* __restrict__ g0, const int* __restrict__ g1,
    const int* __restrict__ g2, const int* __restrict__ g3,
    const int* __restrict__ g4, const int* __restrict__ g5,
    const u16* __restrict__ XT, const float* __restrict__ rs,
    u16* __restrict__ Z){
  const int* gs[6] = {g0, g1, g2, g3, g4, g5};
  int mt = blockIdx.x, b = blockIdx.y, kg = blockIdx.z;
  int m0 = mt * 64;
  const int* G = gs[kg] + ((size_t)(b * Nn + m0)) * Nn;
  const u16* Xb = XT + (size_t)b * Dd * Nn;
  __shared__ u16 As[64 * 72];
  __shared__ u16 Bs[256 * 72];
  int t = threadIdx.x, lane = t & 63, wn = t >> 6;
  f32x4 acc[4][4];
  #pragma unroll
  for (int i = 0; i < 4; ++i)
    #pragma unroll
    for (int q = 0; q < 4; ++q) acc[i][q] = (f32x4){0.f, 0.f, 0.f, 0.f};

  for (int ks = 0; ks < 8; ++ks){
    int k0 = ks * 64;
    { // A stage: 64x64 ints -> bf16 0/1, diag zeroed
      int row = t >> 2, q = t & 3;
      const int* gp = G + (size_t)row * Nn + k0 + q * 16;
      int mg = m0 + row;
      union { u16 h[16]; uint4 v[2]; } pk;
      #pragma unroll
      for (int c = 0; c < 4; ++c){
        int4 gv = ((const int4*)gp)[c];
        int cg = k0 + q * 16 + c * 4;
        pk.h[c * 4 + 0] = (gv.x && (cg + 0) != mg) ? 0x3F80 : 0;
        pk.h[c * 4 + 1] = (gv.y && (cg + 1) != mg) ? 0x3F80 : 0;
        pk.h[c * 4 + 2] = (gv.z && (cg + 2) != mg) ? 0x3F80 : 0;
        pk.h[c * 4 + 3] = (gv.w && (cg + 3) != mg) ? 0x3F80 : 0;
      }
      *(uint4*)&As[row * 72 + q * 16]     = pk.v[0];
      *(uint4*)&As[row * 72 + q * 16 + 8] = pk.v[1];
    }
    // B stage: 256 rows (d) x 64 cols (n-slice) from X'^T
    #pragma unroll
    for (int p = 0; p < 8; ++p){
      int rowb = p * 32 + (t >> 3);
      *(uint4*)&Bs[rowb * 72 + (t & 7) * 8] =
          *(const uint4*)(Xb + (size_t)rowb * Nn + k0 + (t & 7) * 8);
    }
    __syncthreads();
    #pragma unroll
    for (int kk = 0; kk < 2; ++kk){
      bf16x8 av[4], bv[4];
      #pragma unroll
      for (int i = 0; i < 4; ++i)
        av[i] = *(const bf16x8*)&As[(i * 16 + (lane & 15)) * 72 + kk * 32 + (lane >> 4) * 8];
      #pragma unroll
      for (int q = 0; q < 4; ++q)
        bv[q] = *(const bf16x8*)&Bs[(wn * 64 + q * 16 + (lane & 15)) * 72 + kk * 32 + (lane >> 4) * 8];
      #pragma unroll
      for (int i = 0; i < 4; ++i)
        #pragma unroll
        for (int q = 0; q < 4; ++q)
          acc[i][q] = __builtin_amdgcn_mfma_f32_16x16x32_bf16(av[i], bv[q], acc[i][q], 0, 0, 0);
    }
    __syncthreads();
  }
  int kgcol = 256 + kg * 256 + wn * 64;
  #pragma unroll
  for (int i = 0; i < 4; ++i){
    #pragma unroll
    for (int r = 0; r < 4; ++r){
      int mg = m0 + i * 16 + (lane >> 4) * 4 + r;
      float sc = rs[b * Nn + mg];
      u16* zp = Z + ((size_t)(b * Nn + mg)) * KC + kgcol + (lane & 15);
      #pragma unroll
      for (int q = 0; q < 4; ++q)
        zp[q * 16] = f2bf(acc[i][q][r] * sc);
    }
  }
}

// ---------------- K4: update GEMM  out = relu(Z @ Wcat + b_self) ----------
// grid (2, 128): ntile, mtile. BM=128, BN=128, BK=64, 4 waves (2x2)
__global__ __launch_bounds__(256) void k_upd(
    const u16* __restrict__ Z, const u16* __restrict__ wcatT,
    const float* __restrict__ bself, float* __restrict__ outp){
  int n0 = blockIdx.x * 128, m0 = blockIdx.y * 128;
  __shared__ u16 As[128 * 72];
  __shared__ u16 Bs[128 * 72];
  int t = threadIdx.x, lane = t & 63, wid = t >> 6;
  int wm = wid >> 1, wn = wid & 1;
  f32x4 acc[4][4];
  #pragma unroll
  for (int i = 0; i < 4; ++i)
    #pragma unroll
    for (int q = 0; q < 4; ++q) acc[i][q] = (f32x4){0.f, 0.f, 0.f, 0.f};

  for (int ks = 0; ks < 28; ++ks){
    int k0 = ks * 64;
    #pragma unroll
    for (int p = 0; p < 4; ++p){
      int row = p * 32 + (t >> 3);
      *(uint4*)&As[row * 72 + (t & 7) * 8] =
          *(const uint4*)(Z + ((size_t)(m0 + row)) * KC + k0 + (t & 7) * 8);
      *(uint4*)&Bs[row * 72 + (t & 7) * 8] =
          *(const uint4*)(wcatT + ((size_t)(n0 + row)) * KC + k0 + (t & 7) * 8);
    }
    __syncthreads();
    #pragma unroll
    for (int kk = 0; kk < 2; ++kk){
      bf16x8 av[4], bv[4];
      #pragma unroll
      for (int i = 0; i < 4; ++i)
        av[i] = *(const bf16x8*)&As[(wm * 64 + i * 16 + (lane & 15)) * 72 + kk * 32 + (lane >> 4) * 8];
      #pragma unroll
      for (int q = 0; q < 4; ++q)
        bv[q] = *(const bf16x8*)&Bs[(wn * 64 + q * 16 + (lane & 15)) * 72 + kk * 32 + (lane >> 4) * 8];
      #pragma unroll
      for (int i = 0; i < 4; ++i)
        #pragma unroll
        for (int q = 0; q < 4; ++q)
          acc[i][q] = __builtin_amdgcn_mfma_f32_16x16x32_bf16(av[i], bv[q], acc[i][q], 0, 0, 0);
    }
    __syncthreads();
  }
  #pragma unroll
  for (int i = 0; i < 4; ++i){
    #pragma unroll
    for (int r = 0; r < 4; ++r){
      int mg = m0 + wm * 64 + i * 16 + (lane >> 4) * 4 + r;
      #pragma unroll
      for (int q = 0; q < 4; ++q){
        int e = n0 + wn * 64 + q * 16 + (lane & 15);
        float v = acc[i][q][r] + bself[e];
        outp[(size_t)mg * Dd + e] = v > 0.f ? v : 0.f;
      }
    }
  }
}

extern "C" void kernel_launch(void* const* d_in, const int* in_sizes, int n_in,
                              void* d_out, int out_size, void* d_ws, size_t ws_size,
                              hipStream_t stream){
  (void)in_sizes; (void)n_in; (void)out_size; (void)ws_size;
  const float* node  = (const float*)d_in[0];
  const int*   mask  = (const int*)d_in[1];
  const int*   g[6];
  for (int i = 0; i < 6; ++i) g[i] = (const int*)d_in[2 + i];
  const float* wnw   = (const float*)d_in[8];
  const float* bnw   = (const float*)d_in[9];
  const float* wself = (const float*)d_in[10];
  const float* bself = (const float*)d_in[11];
  const float* W[6];
  for (int i = 0; i < 6; ++i) W[i] = (const float*)d_in[12 + i];

  float* out_node = (float*)d_out;
  float* out_aw   = out_node + (size_t)Bb * Nn * Dd;

  char* ws = (char*)d_ws;
  u16*   wcatT    = (u16*)(ws);                          // 917,504 B
  float* rs       = (float*)(ws + (1u << 20));           // 65,536 B
  u16*   XT       = (u16*)(ws + (2u << 20));             // 8 MB
  u16*   Z        = (u16*)(ws + (10u << 20));            // 56 MB
  float* node_buf = (float*)(ws + (66u << 20));          // 16 MB

  k_prep<<<256, 256, 0, stream>>>(wself, W[0], W[1], W[2], W[3], W[4], W[5], wcatT);
  k_nn<<<4096, 256, 0, stream>>>(g[0], g[1], g[2], g[3], g[4], g[5], mask, rs);

  for (int t = 0; t < 2; ++t){
    const float* nsrc = (t == 0) ? node : node_buf;
    float* nout = (t == 0) ? node_buf : out_node;
    k_dw<<<512, 256, 0, stream>>>(nsrc, mask, wnw, bnw, out_aw + t * Nn, Z, XT);
    k_agg<<<dim3(8, 32, 6), 256, 0, stream>>>(g[0], g[1], g[2], g[3], g[4], g[5], XT, rs, Z);
    k_upd<<<dim3(2, 128), 256, 0, stream>>>(Z, wcatT, bself, nout);
  }
}

// Round 2
// 288.881 us; speedup vs baseline: 1.0571x; 1.0571x over previous
//
#include <hip/hip_runtime.h>

#define Bb 32
#define Nn 512
#define Dd 256
#define KC 1792   // 256 (self) + 6*256 (edge types)

typedef __bf16 bf16x8 __attribute__((ext_vector_type(8)));
typedef float  f32x4  __attribute__((ext_vector_type(4)));
typedef unsigned short u16;

__device__ __forceinline__ u16 f2bf(float x){
  union { float f; unsigned u; } c; c.f = x;
  unsigned u = c.u;
  u += 0x7FFFu + ((u >> 16) & 1u);   // RNE
  return (u16)(u >> 16);
}

// ---------------- K0: WcatT[e][c] = Wcat[c][e] in bf16, [256 x 1792] -------
__global__ __launch_bounds__(256) void k_prep(
    const float* __restrict__ wself,
    const float* __restrict__ w0, const float* __restrict__ w1,
    const float* __restrict__ w2, const float* __restrict__ w3,
    const float* __restrict__ w4, const float* __restrict__ w5,
    u16* __restrict__ wcatT){
  int e = blockIdx.x;
  const float* Ws[7] = {wself, w0, w1, w2, w3, w4, w5};
  for (int c = threadIdx.x; c < KC; c += 256){
    int g = c >> 8, j = c & 255;
    wcatT[(size_t)e*KC + c] = f2bf(Ws[g][j*Dd + e]);
  }
}

// ---------------- K1: bitpack graphs (mask+diag folded) + nn popcount ------
// Gp[k][b][m][w]: bit j of word w = G value at col 32w+j. rs = mask/max(nn,1)
__global__ __launch_bounds__(256) void k_pack(
    const int* __restrict__ g0, const int* __restrict__ g1,
    const int* __restrict__ g2, const int* __restrict__ g3,
    const int* __restrict__ g4, const int* __restrict__ g5,
    const int* __restrict__ mask, unsigned* __restrict__ Gp,
    float* __restrict__ rs){
  int wid = threadIdx.x >> 6, l = threadIdx.x & 63;
  int r = blockIdx.x * 4 + wid;          // r = b*512 + m
  int b = r >> 9, m = r & 511;
  const int* gs[6] = {g0, g1, g2, g3, g4, g5};
  int mcol[8];
  #pragma unroll
  for (int h = 0; h < 8; ++h) mcol[h] = mask[b * Nn + h * 64 + l];
  int s = 0;
  #pragma unroll
  for (int k = 0; k < 6; ++k){
    const int* gp = gs[k] + (size_t)r * Nn;
    unsigned my = 0;
    #pragma unroll
    for (int h = 0; h < 8; ++h){
      int col = h * 64 + l;
      int v = gp[col];
      unsigned long long bal = __ballot(v && mcol[h] && col != m);
      s += __popcll(bal);
      if (l == 2 * h)     my = (unsigned)bal;
      if (l == 2 * h + 1) my = (unsigned)(bal >> 32);
    }
    if (l < 16) Gp[((size_t)k * Bb * Nn + r) * 16 + l] = my;
  }
  if (l == 0){
    int mm = mask[r];
    rs[r] = mm ? 1.0f / (float)(s < 1 ? 1 : s) : 0.0f;
  }
}

// ---------------- K2: dw (sigmoid), Z node copy (bf16), X'^T build ---------
__global__ __launch_bounds__(256) void k_dw(
    const float* __restrict__ node, const int* __restrict__ mask,
    const float* __restrict__ wnw, const float* __restrict__ bnw,
    float* __restrict__ aw_out,    // already offset by t*N
    u16* __restrict__ Z, u16* __restrict__ XT){
  __shared__ float tile[32][268];
  __shared__ float dws[32];
  int b = blockIdx.x >> 4, n0 = (blockIdx.x & 15) << 5;
  int t = threadIdx.x;
  int row = t >> 3, seg = t & 7;
  const float* src = node + ((size_t)(b * Nn + n0 + row)) * Dd + seg * 32;
  u16* zn = Z + ((size_t)(b * Nn + n0 + row)) * KC + seg * 32;
  #pragma unroll
  for (int c = 0; c < 8; ++c){
    float4 v = ((const float4*)src)[c];
    tile[row][seg * 32 + c * 4 + 0] = v.x;
    tile[row][seg * 32 + c * 4 + 1] = v.y;
    tile[row][seg * 32 + c * 4 + 2] = v.z;
    tile[row][seg * 32 + c * 4 + 3] = v.w;
    ushort4 h;
    h.x = f2bf(v.x); h.y = f2bf(v.y); h.z = f2bf(v.z); h.w = f2bf(v.w);
    ((ushort4*)zn)[c] = h;
  }
  __syncthreads();
  float s = 0.f;
  #pragma unroll
  for (int c = 0; c < 32; ++c) s += tile[row][seg * 32 + c] * wnw[seg * 32 + c];
  s += __shfl_xor(s, 1); s += __shfl_xor(s, 2); s += __shfl_xor(s, 4);
  if (seg == 0){
    float dw = 1.f / (1.f + expf(-(s + bnw[0])));
    aw_out[b * (2 * Nn) + n0 + row] = dw;
    dws[row] = mask[b * Nn + n0 + row] ? dw : 0.f;
  }
  __syncthreads();
  #pragma unroll
  for (int p = 0; p < 4; ++p){
    int d = p * 64 + (t >> 2);
    int j0 = (t & 3) * 8;
    union { u16 h[8]; uint4 v; } pk;
    #pragma unroll
    for (int jj = 0; jj < 8; ++jj)
      pk.h[jj] = f2bf(dws[j0 + jj] * tile[j0 + jj][d]);
    *(uint4*)(XT + ((size_t)(b * Dd + d)) * Nn + n0 + j0) = pk.v;
  }
}

// ---------------- K3: aggregation GEMM  H'_k = rs * (G_k @ X') ------------
// grid (8, 32, 6): mtile, b, edge-type.  BM=64, BN=256(full D), BK=64, 4 waves
__global__ __launch_bounds__(256) void k_agg(
    const unsigned* __restrict__ Gp,
    const u16* __restrict__ XT, const float* __restrict__ rs,
    u16* __restrict__ Z){
  int mt = blockIdx.x, b = blockIdx.y, kg = blockIdx.z;
  int m0 = mt * 64;
  const unsigned* Gr = Gp + ((size_t)kg * Bb * Nn + b * Nn + m0) * 16;
  const u16* Xb = XT + (size_t)b * Dd * Nn;
  __shared__ u16 As[64 * 72];
  __shared__ u16 Bs[256 * 72];
  int t = threadIdx.x, lane = t & 63, wn = t >> 6;
  int arow = t >> 2, aq = t & 3;
  // preload this thread's 8 packed words (one per K-step), L2-hit
  unsigned wpre[8];
  #pragma unroll
  for (int ks = 0; ks < 8; ++ks)
    wpre[ks] = Gr[arow * 16 + ks * 2 + (aq >> 1)];

  f32x4 acc[4][4];
  #pragma unroll
  for (int i = 0; i < 4; ++i)
    #pragma unroll
    for (int q = 0; q < 4; ++q) acc[i][q] = (f32x4){0.f, 0.f, 0.f, 0.f};

  for (int ks = 0; ks < 8; ++ks){
    int k0 = ks * 64;
    { // A stage: unpack 16 bits -> bf16 0/1
      unsigned bits = (wpre[ks] >> ((aq & 1) * 16)) & 0xFFFFu;
      union { u16 h[16]; uint4 v[2]; } pk;
      #pragma unroll
      for (int c = 0; c < 16; ++c)
        pk.h[c] = ((bits >> c) & 1u) ? 0x3F80 : 0;
      *(uint4*)&As[arow * 72 + aq * 16]     = pk.v[0];
      *(uint4*)&As[arow * 72 + aq * 16 + 8] = pk.v[1];
    }
    // B stage: 256 rows (d) x 64 cols (n-slice) from X'^T
    #pragma unroll
    for (int p = 0; p < 8; ++p){
      int rowb = p * 32 + (t >> 3);
      *(uint4*)&Bs[rowb * 72 + (t & 7) * 8] =
          *(const uint4*)(Xb + (size_t)rowb * Nn + k0 + (t & 7) * 8);
    }
    __syncthreads();
    #pragma unroll
    for (int kk = 0; kk < 2; ++kk){
      bf16x8 av[4], bv[4];
      #pragma unroll
      for (int i = 0; i < 4; ++i)
        av[i] = *(const bf16x8*)&As[(i * 16 + (lane & 15)) * 72 + kk * 32 + (lane >> 4) * 8];
      #pragma unroll
      for (int q = 0; q < 4; ++q)
        bv[q] = *(const bf16x8*)&Bs[(wn * 64 + q * 16 + (lane & 15)) * 72 + kk * 32 + (lane >> 4) * 8];
      #pragma unroll
      for (int i = 0; i < 4; ++i)
        #pragma unroll
        for (int q = 0; q < 4; ++q)
          acc[i][q] = __builtin_amdgcn_mfma_f32_16x16x32_bf16(av[i], bv[q], acc[i][q], 0, 0, 0);
    }
    __syncthreads();
  }
  int kgcol = 256 + kg * 256 + wn * 64;
  #pragma unroll
  for (int i = 0; i < 4; ++i){
    #pragma unroll
    for (int r = 0; r < 4; ++r){
      int mg = m0 + i * 16 + (lane >> 4) * 4 + r;
      float sc = rs[b * Nn + mg];
      u16* zp = Z + ((size_t)(b * Nn + mg)) * KC + kgcol + (lane & 15);
      #pragma unroll
      for (int q = 0; q < 4; ++q)
        zp[q * 16] = f2bf(acc[i][q][r] * sc);
    }
  }
}

// ---------------- K4: update GEMM  out = relu(Z @ Wcat + b_self) ----------
// grid (2, 128): ntile, mtile. BM=128, BN=128, BK=64, 4 waves (2x2)
__global__ __launch_bounds__(256) void k_upd(
    const u16* __restrict__ Z, const u16* __restrict__ wcatT,
    const float* __restrict__ bself, float* __restrict__ outp){
  int n0 = blockIdx.x * 128, m0 = blockIdx.y * 128;
  __shared__ u16 As[128 * 72];
  __shared__ u16 Bs[128 * 72];
  int t = threadIdx.x, lane = t & 63, wid = t >> 6;
  int wm = wid >> 1, wn = wid & 1;
  f32x4 acc[4][4];
  #pragma unroll
  for (int i = 0; i < 4; ++i)
    #pragma unroll
    for (int q = 0; q < 4; ++q) acc[i][q] = (f32x4){0.f, 0.f, 0.f, 0.f};

  for (int ks = 0; ks < 28; ++ks){
    int k0 = ks * 64;
    #pragma unroll
    for (int p = 0; p < 4; ++p){
      int row = p * 32 + (t >> 3);
      *(uint4*)&As[row * 72 + (t & 7) * 8] =
          *(const uint4*)(Z + ((size_t)(m0 + row)) * KC + k0 + (t & 7) * 8);
      *(uint4*)&Bs[row * 72 + (t & 7) * 8] =
          *(const uint4*)(wcatT + ((size_t)(n0 + row)) * KC + k0 + (t & 7) * 8);
    }
    __syncthreads();
    #pragma unroll
    for (int kk = 0; kk < 2; ++kk){
      bf16x8 av[4], bv[4];
      #pragma unroll
      for (int i = 0; i < 4; ++i)
        av[i] = *(const bf16x8*)&As[(wm * 64 + i * 16 + (lane & 15)) * 72 + kk * 32 + (lane >> 4) * 8];
      #pragma unroll
      for (int q = 0; q < 4; ++q)
        bv[q] = *(const bf16x8*)&Bs[(wn * 64 + q * 16 + (lane & 15)) * 72 + kk * 32 + (lane >> 4) * 8];
      #pragma unroll
      for (int i = 0; i < 4; ++i)
        #pragma unroll
        for (int q = 0; q < 4; ++q)
          acc[i][q] = __builtin_amdgcn_mfma_f32_16x16x32_bf16(av[i], bv[q], acc[i][q], 0, 0, 0);
    }
    __syncthreads();
  }
  #pragma unroll
  for (int i = 0; i < 4; ++i){
    #pragma unroll
    for (int r = 0; r < 4; ++r){
      int mg = m0 + wm * 64 + i * 16 + (lane >> 4) * 4 + r;
      #pragma unroll
      for (int q = 0; q < 4; ++q){
        int e = n0 + wn * 64 + q * 16 + (lane & 15);
        float v = acc[i][q][r] + bself[e];
        outp[(size_t)mg * Dd + e] = v > 0.f ? v : 0.f;
      }
    }
  }
}

extern "C" void kernel_launch(void* const* d_in, const int* in_sizes, int n_in,
                              void* d_out, int out_size, void* d_ws, size_t ws_size,
                              hipStream_t stream){
  (void)in_sizes; (void)n_in; (void)out_size; (void)ws_size;
  const float* node  = (const float*)d_in[0];
  const int*   mask  = (const int*)d_in[1];
  const int*   g[6];
  for (int i = 0; i < 6; ++i) g[i] = (const int*)d_in[2 + i];
  const float* wnw   = (const float*)d_in[8];
  const float* bnw   = (const float*)d_in[9];
  const float* wself = (const float*)d_in[10];
  const float* bself = (const float*)d_in[11];
  const float* W[6];
  for (int i = 0; i < 6; ++i) W[i] = (const float*)d_in[12 + i];

  float* out_node = (float*)d_out;
  float* out_aw   = out_node + (size_t)Bb * Nn * Dd;

  char* ws = (char*)d_ws;
  u16*      wcatT = (u16*)(ws);                    // 917,504 B
  float*    rs    = (float*)(ws + 917504);         // 65,536 B
  unsigned* Gp    = (unsigned*)(ws + 1048576);     // 6,291,456 B
  u16*      XT    = (u16*)(ws + 7340032);          // 8,388,608 B
  u16*      Z     = (u16*)(ws + 15728640);         // 58,720,256 B -> ends ~71 MB

  k_prep<<<256, 256, 0, stream>>>(wself, W[0], W[1], W[2], W[3], W[4], W[5], wcatT);
  k_pack<<<4096, 256, 0, stream>>>(g[0], g[1], g[2], g[3], g[4], g[5], mask, Gp, rs);

  for (int t = 0; t < 2; ++t){
    const float* nsrc = (t == 0) ? node : out_node;   // iter-1 result lives in d_out
    k_dw<<<512, 256, 0, stream>>>(nsrc, mask, wnw, bnw, out_aw + t * Nn, Z, XT);
    k_agg<<<dim3(8, 32, 6), 256, 0, stream>>>(Gp, XT, rs, Z);
    k_upd<<<dim3(2, 128), 256, 0, stream>>>(Z, wcatT, bself, out_node);
  }
}

// Round 3
// 247.686 us; speedup vs baseline: 1.2329x; 1.1663x over previous
//
#include <hip/hip_runtime.h>

#define Bb 32
#define Nn 512
#define Dd 256
#define KC 1792   // 256 (self) + 6*256 (edge types)

typedef __bf16 bf16x8 __attribute__((ext_vector_type(8)));
typedef float  f32x4  __attribute__((ext_vector_type(4)));
typedef unsigned short u16;

__device__ __forceinline__ u16 f2bf(float x){
  union { float f; unsigned u; } c; c.f = x;
  unsigned u = c.u;
  u += 0x7FFFu + ((u >> 16) & 1u);   // RNE
  return (u16)(u >> 16);
}

// ---------------- K0: WcatT[e][c] = Wcat[c][e] in bf16, [256 x 1792] -------
__global__ __launch_bounds__(256) void k_prep(
    const float* __restrict__ wself,
    const float* __restrict__ w0, const float* __restrict__ w1,
    const float* __restrict__ w2, const float* __restrict__ w3,
    const float* __restrict__ w4, const float* __restrict__ w5,
    u16* __restrict__ wcatT){
  int e = blockIdx.x;
  const float* Ws[7] = {wself, w0, w1, w2, w3, w4, w5};
  for (int c = threadIdx.x; c < KC; c += 256){
    int g = c >> 8, j = c & 255;
    wcatT[(size_t)e*KC + c] = f2bf(Ws[g][j*Dd + e]);
  }
}

// ---------------- K1: bitpack graphs (mask+diag folded) + nn popcount ------
// One wave = one row r (all 6 graphs). 56 independent loads up front (ILP),
// then 48 ballots; word capture via branchless cndmask; nn sum is scalar.
// Gp[k][b][m][w]: bit j of word w = masked G value at col 32w+j.
__global__ __launch_bounds__(256) void k_pack(
    const int* __restrict__ g0, const int* __restrict__ g1,
    const int* __restrict__ g2, const int* __restrict__ g3,
    const int* __restrict__ g4, const int* __restrict__ g5,
    const int* __restrict__ mask, unsigned* __restrict__ Gp,
    float* __restrict__ rs){
  int wid = threadIdx.x >> 6, l = threadIdx.x & 63;
  int r = blockIdx.x * 4 + wid;          // r = b*512 + m
  int b = r >> 9, m = r & 511;
  const int* gs[6] = {g0, g1, g2, g3, g4, g5};
  const int* mrow = mask + (size_t)b * Nn;

  int mc[8];
  #pragma unroll
  for (int h = 0; h < 8; ++h) mc[h] = mrow[h * 64 + l];

  // all 48 graph dwords for this row, loaded before any ballot (ILP)
  int gv[6][8];
  #pragma unroll
  for (int k = 0; k < 6; ++k){
    const int* gp = gs[k] + (size_t)r * Nn;
    #pragma unroll
    for (int h = 0; h < 8; ++h) gv[k][h] = gp[h * 64 + l];
  }

  int stot = 0;
  int wsel = l >> 1, hsel = l & 1;       // lane l<16 captures word l
  #pragma unroll
  for (int k = 0; k < 6; ++k){
    unsigned my = 0;
    #pragma unroll
    for (int h = 0; h < 8; ++h){
      int col = h * 64 + l;
      unsigned long long bal = __ballot(gv[k][h] && mc[h] && col != m);
      stot += __popcll(bal);
      unsigned cap = hsel ? (unsigned)(bal >> 32) : (unsigned)bal;
      my = (wsel == h) ? cap : my;
    }
    if (l < 16) Gp[((size_t)k * Bb * Nn + r) * 16 + l] = my;
  }
  if (l == 0)
    rs[r] = mrow[m] ? 1.0f / (float)(stot < 1 ? 1 : stot) : 0.0f;
}

// ---------------- K2: dw (sigmoid), Z node copy (bf16), X'^T build ---------
__global__ __launch_bounds__(256) void k_dw(
    const float* __restrict__ node, const int* __restrict__ mask,
    const float* __restrict__ wnw, const float* __restrict__ bnw,
    float* __restrict__ aw_out,    // already offset by t*N
    u16* __restrict__ Z, u16* __restrict__ XT){
  __shared__ float tile[32][268];
  __shared__ float dws[32];
  int b = blockIdx.x >> 4, n0 = (blockIdx.x & 15) << 5;
  int t = threadIdx.x;
  int row = t >> 3, seg = t & 7;
  const float* src = node + ((size_t)(b * Nn + n0 + row)) * Dd + seg * 32;
  u16* zn = Z + ((size_t)(b * Nn + n0 + row)) * KC + seg * 32;
  #pragma unroll
  for (int c = 0; c < 8; ++c){
    float4 v = ((const float4*)src)[c];
    tile[row][seg * 32 + c * 4 + 0] = v.x;
    tile[row][seg * 32 + c * 4 + 1] = v.y;
    tile[row][seg * 32 + c * 4 + 2] = v.z;
    tile[row][seg * 32 + c * 4 + 3] = v.w;
    ushort4 h;
    h.x = f2bf(v.x); h.y = f2bf(v.y); h.z = f2bf(v.z); h.w = f2bf(v.w);
    ((ushort4*)zn)[c] = h;
  }
  __syncthreads();
  float s = 0.f;
  #pragma unroll
  for (int c = 0; c < 32; ++c) s += tile[row][seg * 32 + c] * wnw[seg * 32 + c];
  s += __shfl_xor(s, 1); s += __shfl_xor(s, 2); s += __shfl_xor(s, 4);
  if (seg == 0){
    float dw = 1.f / (1.f + expf(-(s + bnw[0])));
    aw_out[b * (2 * Nn) + n0 + row] = dw;
    dws[row] = mask[b * Nn + n0 + row] ? dw : 0.f;
  }
  __syncthreads();
  #pragma unroll
  for (int p = 0; p < 4; ++p){
    int d = p * 64 + (t >> 2);
    int j0 = (t & 3) * 8;
    union { u16 h[8]; uint4 v; } pk;
    #pragma unroll
    for (int jj = 0; jj < 8; ++jj)
      pk.h[jj] = f2bf(dws[j0 + jj] * tile[j0 + jj][d]);
    *(uint4*)(XT + ((size_t)(b * Dd + d)) * Nn + n0 + j0) = pk.v;
  }
}

// ---------------- K3: aggregation GEMM  H'_k = rs * (G_k @ X') ------------
// grid (8, 32, 6): mtile, b, edge-type.  BM=64, BN=256(full D), BK=64, 4 waves
__global__ __launch_bounds__(256) void k_agg(
    const unsigned* __restrict__ Gp,
    const u16* __restrict__ XT, const float* __restrict__ rs,
    u16* __restrict__ Z){
  int mt = blockIdx.x, b = blockIdx.y, kg = blockIdx.z;
  int m0 = mt * 64;
  const unsigned* Gr = Gp + ((size_t)kg * Bb * Nn + b * Nn + m0) * 16;
  const u16* Xb = XT + (size_t)b * Dd * Nn;
  __shared__ u16 As[64 * 72];
  __shared__ u16 Bs[256 * 72];
  int t = threadIdx.x, lane = t & 63, wn = t >> 6;
  int arow = t >> 2, aq = t & 3;
  // preload this thread's 8 packed words (one per K-step), L2-hit
  unsigned wpre[8];
  #pragma unroll
  for (int ks = 0; ks < 8; ++ks)
    wpre[ks] = Gr[arow * 16 + ks * 2 + (aq >> 1)];

  f32x4 acc[4][4];
  #pragma unroll
  for (int i = 0; i < 4; ++i)
    #pragma unroll
    for (int q = 0; q < 4; ++q) acc[i][q] = (f32x4){0.f, 0.f, 0.f, 0.f};

  for (int ks = 0; ks < 8; ++ks){
    int k0 = ks * 64;
    { // A stage: unpack 16 bits -> bf16 0/1
      unsigned bits = (wpre[ks] >> ((aq & 1) * 16)) & 0xFFFFu;
      union { u16 h[16]; uint4 v[2]; } pk;
      #pragma unroll
      for (int c = 0; c < 16; ++c)
        pk.h[c] = ((bits >> c) & 1u) ? 0x3F80 : 0;
      *(uint4*)&As[arow * 72 + aq * 16]     = pk.v[0];
      *(uint4*)&As[arow * 72 + aq * 16 + 8] = pk.v[1];
    }
    // B stage: 256 rows (d) x 64 cols (n-slice) from X'^T
    #pragma unroll
    for (int p = 0; p < 8; ++p){
      int rowb = p * 32 + (t >> 3);
      *(uint4*)&Bs[rowb * 72 + (t & 7) * 8] =
          *(const uint4*)(Xb + (size_t)rowb * Nn + k0 + (t & 7) * 8);
    }
    __syncthreads();
    #pragma unroll
    for (int kk = 0; kk < 2; ++kk){
      bf16x8 av[4], bv[4];
      #pragma unroll
      for (int i = 0; i < 4; ++i)
        av[i] = *(const bf16x8*)&As[(i * 16 + (lane & 15)) * 72 + kk * 32 + (lane >> 4) * 8];
      #pragma unroll
      for (int q = 0; q < 4; ++q)
        bv[q] = *(const bf16x8*)&Bs[(wn * 64 + q * 16 + (lane & 15)) * 72 + kk * 32 + (lane >> 4) * 8];
      #pragma unroll
      for (int i = 0; i < 4; ++i)
        #pragma unroll
        for (int q = 0; q < 4; ++q)
          acc[i][q] = __builtin_amdgcn_mfma_f32_16x16x32_bf16(av[i], bv[q], acc[i][q], 0, 0, 0);
    }
    __syncthreads();
  }
  int kgcol = 256 + kg * 256 + wn * 64;
  #pragma unroll
  for (int i = 0; i < 4; ++i){
    #pragma unroll
    for (int r = 0; r < 4; ++r){
      int mg = m0 + i * 16 + (lane >> 4) * 4 + r;
      float sc = rs[b * Nn + mg];
      u16* zp = Z + ((size_t)(b * Nn + mg)) * KC + kgcol + (lane & 15);
      #pragma unroll
      for (int q = 0; q < 4; ++q)
        zp[q * 16] = f2bf(acc[i][q][r] * sc);
    }
  }
}

// ---------------- K4: update GEMM  out = relu(Z @ Wcat + b_self) ----------
// grid (2, 128): ntile, mtile. BM=128, BN=128, BK=64, 4 waves (2x2)
__global__ __launch_bounds__(256) void k_upd(
    const u16* __restrict__ Z, const u16* __restrict__ wcatT,
    const float* __restrict__ bself, float* __restrict__ outp){
  int n0 = blockIdx.x * 128, m0 = blockIdx.y * 128;
  __shared__ u16 As[128 * 72];
  __shared__ u16 Bs[128 * 72];
  int t = threadIdx.x, lane = t & 63, wid = t >> 6;
  int wm = wid >> 1, wn = wid & 1;
  f32x4 acc[4][4];
  #pragma unroll
  for (int i = 0; i < 4; ++i)
    #pragma unroll
    for (int q = 0; q < 4; ++q) acc[i][q] = (f32x4){0.f, 0.f, 0.f, 0.f};

  for (int ks = 0; ks < 28; ++ks){
    int k0 = ks * 64;
    #pragma unroll
    for (int p = 0; p < 4; ++p){
      int row = p * 32 + (t >> 3);
      *(uint4*)&As[row * 72 + (t & 7) * 8] =
          *(const uint4*)(Z + ((size_t)(m0 + row)) * KC + k0 + (t & 7) * 8);
      *(uint4*)&Bs[row * 72 + (t & 7) * 8] =
          *(const uint4*)(wcatT + ((size_t)(n0 + row)) * KC + k0 + (t & 7) * 8);
    }
    __syncthreads();
    #pragma unroll
    for (int kk = 0; kk < 2; ++kk){
      bf16x8 av[4], bv[4];
      #pragma unroll
      for (int i = 0; i < 4; ++i)
        av[i] = *(const bf16x8*)&As[(wm * 64 + i * 16 + (lane & 15)) * 72 + kk * 32 + (lane >> 4) * 8];
      #pragma unroll
      for (int q = 0; q < 4; ++q)
        bv[q] = *(const bf16x8*)&Bs[(wn * 64 + q * 16 + (lane & 15)) * 72 + kk * 32 + (lane >> 4) * 8];
      #pragma unroll
      for (int i = 0; i < 4; ++i)
        #pragma unroll
        for (int q = 0; q < 4; ++q)
          acc[i][q] = __builtin_amdgcn_mfma_f32_16x16x32_bf16(av[i], bv[q], acc[i][q], 0, 0, 0);
    }
    __syncthreads();
  }
  #pragma unroll
  for (int i = 0; i < 4; ++i){
    #pragma unroll
    for (int r = 0; r < 4; ++r){
      int mg = m0 + wm * 64 + i * 16 + (lane >> 4) * 4 + r;
      #pragma unroll
      for (int q = 0; q < 4; ++q){
        int e = n0 + wn * 64 + q * 16 + (lane & 15);
        float v = acc[i][q][r] + bself[e];
        outp[(size_t)mg * Dd + e] = v > 0.f ? v : 0.f;
      }
    }
  }
}

extern "C" void kernel_launch(void* const* d_in, const int* in_sizes, int n_in,
                              void* d_out, int out_size, void* d_ws, size_t ws_size,
                              hipStream_t stream){
  (void)in_sizes; (void)n_in; (void)out_size; (void)ws_size;
  const float* node  = (const float*)d_in[0];
  const int*   mask  = (const int*)d_in[1];
  const int*   g[6];
  for (int i = 0; i < 6; ++i) g[i] = (const int*)d_in[2 + i];
  const float* wnw   = (const float*)d_in[8];
  const float* bnw   = (const float*)d_in[9];
  const float* wself = (const float*)d_in[10];
  const float* bself = (const float*)d_in[11];
  const float* W[6];
  for (int i = 0; i < 6; ++i) W[i] = (const float*)d_in[12 + i];

  float* out_node = (float*)d_out;
  float* out_aw   = out_node + (size_t)Bb * Nn * Dd;

  char* ws = (char*)d_ws;
  u16*      wcatT = (u16*)(ws);                    // 917,504 B
  float*    rs    = (float*)(ws + 917504);         // 65,536 B
  unsigned* Gp    = (unsigned*)(ws + 1048576);     // 6,291,456 B
  u16*      XT    = (u16*)(ws + 7340032);          // 8,388,608 B
  u16*      Z     = (u16*)(ws + 15728640);         // 58,720,256 B -> ends ~71 MB

  k_prep<<<256, 256, 0, stream>>>(wself, W[0], W[1], W[2], W[3], W[4], W[5], wcatT);
  k_pack<<<4096, 256, 0, stream>>>(g[0], g[1], g[2], g[3], g[4], g[5], mask, Gp, rs);

  for (int t = 0; t < 2; ++t){
    const float* nsrc = (t == 0) ? node : out_node;   // iter-1 result lives in d_out
    k_dw<<<512, 256, 0, stream>>>(nsrc, mask, wnw, bnw, out_aw + t * Nn, Z, XT);
    k_agg<<<dim3(8, 32, 6), 256, 0, stream>>>(Gp, XT, rs, Z);
    k_upd<<<dim3(2, 128), 256, 0, stream>>>(Z, wcatT, bself, out_node);
  }
}

// Round 4
// 246.397 us; speedup vs baseline: 1.2393x; 1.0052x over previous
//
#include <hip/hip_runtime.h>

#define Bb 32
#define Nn 512
#define Dd 256
#define KC 1792   // 256 (self) + 6*256 (edge types)

typedef __bf16 bf16x8 __attribute__((ext_vector_type(8)));
typedef float  f32x4  __attribute__((ext_vector_type(4)));
typedef unsigned short u16;

__device__ __forceinline__ u16 f2bf(float x){
  union { float f; unsigned u; } c; c.f = x;
  unsigned u = c.u;
  u += 0x7FFFu + ((u >> 16) & 1u);   // RNE
  return (u16)(u >> 16);
}

// ---------------- K0: WcatT[e][c] = Wcat[c][e] in bf16, [256 x 1792] -------
__global__ __launch_bounds__(256) void k_prep(
    const float* __restrict__ wself,
    const float* __restrict__ w0, const float* __restrict__ w1,
    const float* __restrict__ w2, const float* __restrict__ w3,
    const float* __restrict__ w4, const float* __restrict__ w5,
    u16* __restrict__ wcatT){
  int e = blockIdx.x;
  const float* Ws[7] = {wself, w0, w1, w2, w3, w4, w5};
  for (int c = threadIdx.x; c < KC; c += 256){
    int g = c >> 8, j = c & 255;
    wcatT[(size_t)e*KC + c] = f2bf(Ws[g][j*Dd + e]);
  }
}

// ---------------- K1: bitpack graphs (mask+diag folded) + nn popcount ------
// One wave = one row r, all 6 graphs. 14 int4 loads up front (full ILP),
// nibble per lane via bit-ops, 3-step shuffle-OR butterfly packs 32-bit words.
// Gp[k][b][m][w]: bit j of word w = masked G value at col 32w+j (unchanged).
__global__ __launch_bounds__(256) void k_pack(
    const int* __restrict__ g0, const int* __restrict__ g1,
    const int* __restrict__ g2, const int* __restrict__ g3,
    const int* __restrict__ g4, const int* __restrict__ g5,
    const int* __restrict__ mask, unsigned* __restrict__ Gp,
    float* __restrict__ rs){
  int wid = threadIdx.x >> 6, l = threadIdx.x & 63;
  int r = blockIdx.x * 4 + wid;          // r = b*512 + m
  int b = r >> 9, m = r & 511;
  const int* gs[6] = {g0, g1, g2, g3, g4, g5};
  const int* mrow = mask + (size_t)b * Nn;

  // chunk h2 covers cols 256*h2 .. 256*h2+255; lane l holds cols 4l..4l+3
  int4 mc[2];
  mc[0] = ((const int4*)mrow)[l];
  mc[1] = ((const int4*)mrow)[64 + l];
  int4 ga[12];
  #pragma unroll
  for (int k = 0; k < 6; ++k){
    const int4* gp = (const int4*)(gs[k] + (size_t)r * Nn);
    ga[k * 2 + 0] = gp[l];
    ga[k * 2 + 1] = gp[64 + l];
  }

  int s1 = (l & 1) * 4, s2 = ((l >> 1) & 1) * 8, s3 = ((l >> 2) & 1) * 16;
  int stot = 0;
  #pragma unroll
  for (int k = 0; k < 6; ++k){
    #pragma unroll
    for (int h2 = 0; h2 < 2; ++h2){
      int4 g = ga[k * 2 + h2], mm = mc[h2];
      unsigned nib = (unsigned)((g.x & mm.x) | ((g.y & mm.y) << 1) |
                                ((g.z & mm.z) << 2) | ((g.w & mm.w) << 3));
      unsigned dm = ((m >> 2) == (h2 * 64 + l)) ? (1u << (m & 3)) : 0u;
      nib &= ~dm;
      stot += __popc(nib);
      unsigned v = nib << s1;  v |= (unsigned)__shfl_xor((int)v, 1);
      v <<= s2;                v |= (unsigned)__shfl_xor((int)v, 2);
      v <<= s3;                v |= (unsigned)__shfl_xor((int)v, 4);
      // lanes with (l&7)==0 hold word (l>>3) of this 256-col chunk
      if ((l & 7) == 0)
        Gp[((size_t)k * Bb * Nn + r) * 16 + h2 * 8 + (l >> 3)] = v;
    }
  }
  #pragma unroll
  for (int off = 1; off < 64; off <<= 1) stot += __shfl_xor(stot, off);
  if (l == 0)
    rs[r] = mrow[m] ? 1.0f / (float)(stot < 1 ? 1 : stot) : 0.0f;
}

// ---------------- K2: dw (sigmoid), Z node copy (bf16), X'^T build ---------
__global__ __launch_bounds__(256) void k_dw(
    const float* __restrict__ node, const int* __restrict__ mask,
    const float* __restrict__ wnw, const float* __restrict__ bnw,
    float* __restrict__ aw_out,    // already offset by t*N
    u16* __restrict__ Z, u16* __restrict__ XT){
  __shared__ float tile[32][268];
  __shared__ float dws[32];
  int b = blockIdx.x >> 4, n0 = (blockIdx.x & 15) << 5;
  int t = threadIdx.x;
  int row = t >> 3, seg = t & 7;
  const float* src = node + ((size_t)(b * Nn + n0 + row)) * Dd + seg * 32;
  u16* zn = Z + ((size_t)(b * Nn + n0 + row)) * KC + seg * 32;
  #pragma unroll
  for (int c = 0; c < 8; ++c){
    float4 v = ((const float4*)src)[c];
    tile[row][seg * 32 + c * 4 + 0] = v.x;
    tile[row][seg * 32 + c * 4 + 1] = v.y;
    tile[row][seg * 32 + c * 4 + 2] = v.z;
    tile[row][seg * 32 + c * 4 + 3] = v.w;
    ushort4 h;
    h.x = f2bf(v.x); h.y = f2bf(v.y); h.z = f2bf(v.z); h.w = f2bf(v.w);
    ((ushort4*)zn)[c] = h;
  }
  __syncthreads();
  float s = 0.f;
  #pragma unroll
  for (int c = 0; c < 32; ++c) s += tile[row][seg * 32 + c] * wnw[seg * 32 + c];
  s += __shfl_xor(s, 1); s += __shfl_xor(s, 2); s += __shfl_xor(s, 4);
  if (seg == 0){
    float dw = 1.f / (1.f + expf(-(s + bnw[0])));
    aw_out[b * (2 * Nn) + n0 + row] = dw;
    dws[row] = mask[b * Nn + n0 + row] ? dw : 0.f;
  }
  __syncthreads();
  #pragma unroll
  for (int p = 0; p < 4; ++p){
    int d = p * 64 + (t >> 2);
    int j0 = (t & 3) * 8;
    union { u16 h[8]; uint4 v; } pk;
    #pragma unroll
    for (int jj = 0; jj < 8; ++jj)
      pk.h[jj] = f2bf(dws[j0 + jj] * tile[j0 + jj][d]);
    *(uint4*)(XT + ((size_t)(b * Dd + d)) * Nn + n0 + j0) = pk.v;
  }
}

// ---------------- K3: aggregation GEMM  H'_k = rs * (G_k @ X') ------------
// grid (8, 32, 6): mtile, b, edge-type.  BM=64, BN=256(full D), BK=64, 4 waves
__global__ __launch_bounds__(256) void k_agg(
    const unsigned* __restrict__ Gp,
    const u16* __restrict__ XT, const float* __restrict__ rs,
    u16* __restrict__ Z){
  int mt = blockIdx.x, b = blockIdx.y, kg = blockIdx.z;
  int m0 = mt * 64;
  const unsigned* Gr = Gp + ((size_t)kg * Bb * Nn + b * Nn + m0) * 16;
  const u16* Xb = XT + (size_t)b * Dd * Nn;
  __shared__ u16 As[64 * 72];
  __shared__ u16 Bs[256 * 72];
  int t = threadIdx.x, lane = t & 63, wn = t >> 6;
  int arow = t >> 2, aq = t & 3;
  // preload this thread's 8 packed words (one per K-step), L2-hit
  unsigned wpre[8];
  #pragma unroll
  for (int ks = 0; ks < 8; ++ks)
    wpre[ks] = Gr[arow * 16 + ks * 2 + (aq >> 1)];

  f32x4 acc[4][4];
  #pragma unroll
  for (int i = 0; i < 4; ++i)
    #pragma unroll
    for (int q = 0; q < 4; ++q) acc[i][q] = (f32x4){0.f, 0.f, 0.f, 0.f};

  for (int ks = 0; ks < 8; ++ks){
    int k0 = ks * 64;
    { // A stage: unpack 16 bits -> bf16 0/1
      unsigned bits = (wpre[ks] >> ((aq & 1) * 16)) & 0xFFFFu;
      union { u16 h[16]; uint4 v[2]; } pk;
      #pragma unroll
      for (int c = 0; c < 16; ++c)
        pk.h[c] = ((bits >> c) & 1u) ? 0x3F80 : 0;
      *(uint4*)&As[arow * 72 + aq * 16]     = pk.v[0];
      *(uint4*)&As[arow * 72 + aq * 16 + 8] = pk.v[1];
    }
    // B stage: 256 rows (d) x 64 cols (n-slice) from X'^T
    #pragma unroll
    for (int p = 0; p < 8; ++p){
      int rowb = p * 32 + (t >> 3);
      *(uint4*)&Bs[rowb * 72 + (t & 7) * 8] =
          *(const uint4*)(Xb + (size_t)rowb * Nn + k0 + (t & 7) * 8);
    }
    __syncthreads();
    #pragma unroll
    for (int kk = 0; kk < 2; ++kk){
      bf16x8 av[4], bv[4];
      #pragma unroll
      for (int i = 0; i < 4; ++i)
        av[i] = *(const bf16x8*)&As[(i * 16 + (lane & 15)) * 72 + kk * 32 + (lane >> 4) * 8];
      #pragma unroll
      for (int q = 0; q < 4; ++q)
        bv[q] = *(const bf16x8*)&Bs[(wn * 64 + q * 16 + (lane & 15)) * 72 + kk * 32 + (lane >> 4) * 8];
      #pragma unroll
      for (int i = 0; i < 4; ++i)
        #pragma unroll
        for (int q = 0; q < 4; ++q)
          acc[i][q] = __builtin_amdgcn_mfma_f32_16x16x32_bf16(av[i], bv[q], acc[i][q], 0, 0, 0);
    }
    __syncthreads();
  }
  int kgcol = 256 + kg * 256 + wn * 64;
  #pragma unroll
  for (int i = 0; i < 4; ++i){
    #pragma unroll
    for (int r = 0; r < 4; ++r){
      int mg = m0 + i * 16 + (lane >> 4) * 4 + r;
      float sc = rs[b * Nn + mg];
      u16* zp = Z + ((size_t)(b * Nn + mg)) * KC + kgcol + (lane & 15);
      #pragma unroll
      for (int q = 0; q < 4; ++q)
        zp[q * 16] = f2bf(acc[i][q][r] * sc);
    }
  }
}

// ---------------- K4: update GEMM  out = relu(Z @ Wcat + b_self) ----------
// grid (2, 128): ntile, mtile. BM=128, BN=128, BK=64, 4 waves (2x2)
__global__ __launch_bounds__(256) void k_upd(
    const u16* __restrict__ Z, const u16* __restrict__ wcatT,
    const float* __restrict__ bself, float* __restrict__ outp){
  int n0 = blockIdx.x * 128, m0 = blockIdx.y * 128;
  __shared__ u16 As[128 * 72];
  __shared__ u16 Bs[128 * 72];
  int t = threadIdx.x, lane = t & 63, wid = t >> 6;
  int wm = wid >> 1, wn = wid & 1;
  f32x4 acc[4][4];
  #pragma unroll
  for (int i = 0; i < 4; ++i)
    #pragma unroll
    for (int q = 0; q < 4; ++q) acc[i][q] = (f32x4){0.f, 0.f, 0.f, 0.f};

  for (int ks = 0; ks < 28; ++ks){
    int k0 = ks * 64;
    #pragma unroll
    for (int p = 0; p < 4; ++p){
      int row = p * 32 + (t >> 3);
      *(uint4*)&As[row * 72 + (t & 7) * 8] =
          *(const uint4*)(Z + ((size_t)(m0 + row)) * KC + k0 + (t & 7) * 8);
      *(uint4*)&Bs[row * 72 + (t & 7) * 8] =
          *(const uint4*)(wcatT + ((size_t)(n0 + row)) * KC + k0 + (t & 7) * 8);
    }
    __syncthreads();
    #pragma unroll
    for (int kk = 0; kk < 2; ++kk){
      bf16x8 av[4], bv[4];
      #pragma unroll
      for (int i = 0; i < 4; ++i)
        av[i] = *(const bf16x8*)&As[(wm * 64 + i * 16 + (lane & 15)) * 72 + kk * 32 + (lane >> 4) * 8];
      #pragma unroll
      for (int q = 0; q < 4; ++q)
        bv[q] = *(const bf16x8*)&Bs[(wn * 64 + q * 16 + (lane & 15)) * 72 + kk * 32 + (lane >> 4) * 8];
      #pragma unroll
      for (int i = 0; i < 4; ++i)
        #pragma unroll
        for (int q = 0; q < 4; ++q)
          acc[i][q] = __builtin_amdgcn_mfma_f32_16x16x32_bf16(av[i], bv[q], acc[i][q], 0, 0, 0);
    }
    __syncthreads();
  }
  #pragma unroll
  for (int i = 0; i < 4; ++i){
    #pragma unroll
    for (int r = 0; r < 4; ++r){
      int mg = m0 + wm * 64 + i * 16 + (lane >> 4) * 4 + r;
      #pragma unroll
      for (int q = 0; q < 4; ++q){
        int e = n0 + wn * 64 + q * 16 + (lane & 15);
        float v = acc[i][q][r] + bself[e];
        outp[(size_t)mg * Dd + e] = v > 0.f ? v : 0.f;
      }
    }
  }
}

extern "C" void kernel_launch(void* const* d_in, const int* in_sizes, int n_in,
                              void* d_out, int out_size, void* d_ws, size_t ws_size,
                              hipStream_t stream){
  (void)in_sizes; (void)n_in; (void)out_size; (void)ws_size;
  const float* node  = (const float*)d_in[0];
  const int*   mask  = (const int*)d_in[1];
  const int*   g[6];
  for (int i = 0; i < 6; ++i) g[i] = (const int*)d_in[2 + i];
  const float* wnw   = (const float*)d_in[8];
  const float* bnw   = (const float*)d_in[9];
  const float* wself = (const float*)d_in[10];
  const float* bself = (const float*)d_in[11];
  const float* W[6];
  for (int i = 0; i < 6; ++i) W[i] = (const float*)d_in[12 + i];

  float* out_node = (float*)d_out;
  float* out_aw   = out_node + (size_t)Bb * Nn * Dd;

  char* ws = (char*)d_ws;
  u16*      wcatT = (u16*)(ws);                    // 917,504 B
  float*    rs    = (float*)(ws + 917504);         // 65,536 B
  unsigned* Gp    = (unsigned*)(ws + 1048576);     // 6,291,456 B
  u16*      XT    = (u16*)(ws + 7340032);          // 8,388,608 B
  u16*      Z     = (u16*)(ws + 15728640);         // 58,720,256 B -> ends ~71 MB

  k_prep<<<256, 256, 0, stream>>>(wself, W[0], W[1], W[2], W[3], W[4], W[5], wcatT);
  k_pack<<<4096, 256, 0, stream>>>(g[0], g[1], g[2], g[3], g[4], g[5], mask, Gp, rs);

  for (int t = 0; t < 2; ++t){
    const float* nsrc = (t == 0) ? node : out_node;   // iter-1 result lives in d_out
    k_dw<<<512, 256, 0, stream>>>(nsrc, mask, wnw, bnw, out_aw + t * Nn, Z, XT);
    k_agg<<<dim3(8, 32, 6), 256, 0, stream>>>(Gp, XT, rs, Z);
    k_upd<<<dim3(2, 128), 256, 0, stream>>>(Z, wcatT, bself, out_node);
  }
}